// Round 16
// baseline (103.152 us; speedup 1.0000x reference)
//
#include <hip/hip_runtime.h>

#define DIN 768

typedef float f2 __attribute__((ext_vector_type(2)));
typedef int i2v __attribute__((ext_vector_type(2)));

#if __has_builtin(__builtin_amdgcn_permlane32_swap)
#define HAVE_PL32 1
#endif
#if __has_builtin(__builtin_amdgcn_permlane16_swap)
#define HAVE_PL16 1
#endif

__device__ __forceinline__ int f2i(float v) { return __builtin_bit_cast(int, v); }
__device__ __forceinline__ float i2f(int v) { return __builtin_bit_cast(float, v); }

// DPP ctrl: quad_perm xor1 = 0xB1 ; xor2 = 0x4E ; row_ror:4 = 0x124 ; row_ror:8 = 0x128
template<int CTRL>
__device__ __forceinline__ float dppf(float v) {
  const int i = f2i(v);
  return i2f(__builtin_amdgcn_update_dpp(i, i, CTRL, 0xF, 0xF, true));
}
template<int CTRL>
__device__ __forceinline__ f2 dppf2(f2 v) {
  f2 r; r.x = dppf<CTRL>(v.x); r.y = dppf<CTRL>(v.y); return r;
}

// Full 64-lane sum of both f2 components. Zero DS ops. (Used once, for sumsq.)
__device__ __forceinline__ f2 wsum2(f2 v) {
  v += dppf2<0xB1>(v);
  v += dppf2<0x4E>(v);
  v += dppf2<0x124>(v);
  v += dppf2<0x128>(v);
#ifdef HAVE_PL16
  { i2v rx = __builtin_amdgcn_permlane16_swap(f2i(v.x), f2i(v.x), false, false);
    i2v ry = __builtin_amdgcn_permlane16_swap(f2i(v.y), f2i(v.y), false, false);
    v.x = i2f(rx.x) + i2f(rx.y);
    v.y = i2f(ry.x) + i2f(ry.y); }
#else
  v.x += __shfl_xor(v.x, 16); v.y += __shfl_xor(v.y, 16);
#endif
#ifdef HAVE_PL32
  { i2v rx = __builtin_amdgcn_permlane32_swap(f2i(v.x), f2i(v.x), false, false);
    i2v ry = __builtin_amdgcn_permlane32_swap(f2i(v.y), f2i(v.y), false, false);
    v.x = i2f(rx.x) + i2f(rx.y);
    v.y = i2f(ry.x) + i2f(ry.y); }
#else
  v.x += __shfl_xor(v.x, 32); v.y += __shfl_xor(v.y, 32);
#endif
  return v;
}

// xor-shuffle of an f2, VALU-only for masks 1,2,16,32.
template<int MASK>
__device__ __forceinline__ f2 shflx_f2(f2 v, int lane) {
  f2 r;
  if constexpr (MASK == 1) {
    r = dppf2<0xB1>(v);
  } else if constexpr (MASK == 2) {
    r = dppf2<0x4E>(v);
  } else if constexpr (MASK == 16) {
#ifdef HAVE_PL16
    const i2v a = __builtin_amdgcn_permlane16_swap(f2i(v.x), f2i(v.x), false, false);
    const i2v b = __builtin_amdgcn_permlane16_swap(f2i(v.y), f2i(v.y), false, false);
    const bool hi = (lane >> 4) & 1;
    r.x = hi ? i2f(a.x) : i2f(a.y);
    r.y = hi ? i2f(b.x) : i2f(b.y);
#else
    r.x = __shfl_xor(v.x, 16); r.y = __shfl_xor(v.y, 16);
#endif
  } else if constexpr (MASK == 32) {
#ifdef HAVE_PL32
    const i2v a = __builtin_amdgcn_permlane32_swap(f2i(v.x), f2i(v.x), false, false);
    const i2v b = __builtin_amdgcn_permlane32_swap(f2i(v.y), f2i(v.y), false, false);
    const bool lo = lane < 32;
    r.x = lo ? i2f(a.y) : i2f(a.x);
    r.y = lo ? i2f(b.y) : i2f(b.x);
#else
    r.x = __shfl_xor(v.x, 32); r.y = __shfl_xor(v.y, 32);
#endif
  } else {
    r.x = __shfl_xor(v.x, MASK); r.y = __shfl_xor(v.y, MASK);
  }
  return r;
}

// LDS address swizzle (GF(2)-linear: swzf(a^b) = swzf(a)^swzf(b))
__device__ __forceinline__ int swzf(int i) { return i ^ ((i >> 4) & 31); }

// Composite gather map of the CNOT ring CNOT(0,1)..CNOT(9,0): Final[i] = In[cnotL(i)]
// GF(2)-linear: every output bit is an XOR of input bits.
__device__ __forceinline__ int cnotL(int i) {
  const int b9 = (i >> 9) & 1;
  const int b8 = (i >> 8) & 1;
  const int b0 = i & 1;
  return ((i ^ (i >> 1)) & 0xFF) | ((b8 ^ b9 ^ b0) << 8) | ((b9 ^ b0) << 9);
}

// RY on a 16-reg component array (rows packed in f2). Real 2x2 acts per component.
template<int RB>
__device__ __forceinline__ void ry1(f2 (&a)[16], float c, float s) {
#pragma unroll
  for (int r = 0; r < 16; ++r) {
    if (!(r & (1 << RB))) {
      const int p = r | (1 << RB);
      const f2 a0 = a[r], a1 = a[p];
      a[r] = a0 * c - a1 * s;
      a[p] = a1 * c + a0 * s;
    }
  }
}
template<int RB>
__device__ __forceinline__ void ry2(f2 (&re)[16], f2 (&im)[16], float c, float s) {
  ry1<RB>(re, c, s);
  ry1<RB>(im, c, s);
}
template<int MASK>
__device__ __forceinline__ void ry1_shfl(int lane, f2 (&a)[16], float c, float s) {
  const float ss = (lane & MASK) ? s : -s;
#pragma unroll
  for (int r = 0; r < 16; ++r) {
    const f2 p = shflx_f2<MASK>(a[r], lane);
    a[r] = a[r] * c + p * ss;
  }
}

// X/Y accumulate, register-pair qubit (each unordered pair once -> fac 2 at output)
template<int RB>
__device__ __forceinline__ void xyr(const f2 (&re)[16], const f2 (&im)[16], f2& aX, f2& aY) {
#pragma unroll
  for (int r = 0; r < 16; ++r) {
    if (!(r & (1 << RB))) {
      const int p = r | (1 << RB);
      aX += re[r] * re[p] + im[r] * im[p];
      aY += re[r] * im[p] - im[r] * re[p];
    }
  }
}
// X/Y accumulate, lane-bit qubit (each ordered pair counted -> net 2x already)
template<int MASK>
__device__ __forceinline__ void xys(int lane, const f2 (&re)[16], const f2 (&im)[16], f2& aX, f2& aY) {
  const float sgn = (lane & MASK) ? -1.f : 1.f;
#pragma unroll
  for (int r = 0; r < 16; ++r) {
    const f2 pr = shflx_f2<MASK>(re[r], lane);
    const f2 pi = shflx_f2<MASK>(im[r], lane);
    aX += re[r] * pr + im[r] * pi;
    aY += (re[r] * pi - im[r] * pr) * sgn;
  }
}

// ---------------- prep kernel: all weight-dependent transcendentals ----------------
// ws layout (float2):
//   [0..69]    gate table ([50..55] FULL-angle Heisenberg; [60..69] folded RY)
//   [70..85]   rz1 r-factor  (cos,sin) of phi_r(r)   — i bits 9..6 (qubits 0..3)
//   [86..101]  rz2 r-factor
//   [102..165] rz1 lane-factor (cos,sin) of phi_l(l) — i bits 5..0 (qubits 4..9)
//   [166..229] rz2 lane-factor
// phi(i) = phi_r(i>>6) + phi_l(i&63), so e^{i phi} = Rf * Lf (complex product).
__global__ void qae_prep(const float* __restrict__ w, float2* __restrict__ ws) {
  const int i = threadIdx.x;          // 0..1023
  if (i < 50) {                       // half-angle gate coefficients
    float s, c; __sincosf(0.5f * w[i], &s, &c);
    ws[i] = make_float2(c, s);
  } else if (i < 56) {                // FULL angle: Heisenberg output transform w[50..55]
    float s, c; __sincosf(w[i], &s, &c);
    ws[i] = make_float2(c, s);
  } else if (i < 60) {
    ws[i] = make_float2(1.f, 0.f);    // unused
  } else if (i < 70) {                // folded RY_b(layer1)+RY_c(layer2)
    const int q = i - 60;
    float s, c; __sincosf(0.5f * (w[20 + q] + w[30 + q]), &s, &c);
    ws[i] = make_float2(c, s);
  }
  if (i < 16) {                       // r-factors: i bit (6+k) ↔ r bit k
    float p1 = 0.f, p2 = 0.f;
#pragma unroll
    for (int k = 0; k < 4; ++k) {
      const float sg = ((i >> k) & 1) ? 0.5f : -0.5f;
      p1 += sg * w[10 + 3 - k];       // w[10 + 9 - (6+k)]
      p2 += sg * w[40 + 3 - k];
    }
    float s, c;
    __sincosf(p1, &s, &c); ws[70 + i] = make_float2(c, s);
    __sincosf(p2, &s, &c); ws[86 + i] = make_float2(c, s);
  }
  if (i < 64) {                       // lane-factors: i bit b ↔ lane bit b (b=0..5)
    float p1 = 0.f, p2 = 0.f;
#pragma unroll
    for (int b = 0; b < 6; ++b) {
      const float sg = ((i >> b) & 1) ? 0.5f : -0.5f;
      p1 += sg * w[10 + 9 - b];
      p2 += sg * w[40 + 9 - b];
    }
    float s, c;
    __sincosf(p1, &s, &c); ws[102 + i] = make_float2(c, s);
    __sincosf(p2, &s, &c); ws[166 + i] = make_float2(c, s);
  }
}

// LDS access at a byte offset (bases XOR compile-time constants)
#define STC8(boff) (*reinterpret_cast<f2*>(reinterpret_cast<char*>(stc) + (boff)))

// -------- main kernel: ONE wave per block (8KB LDS), 2 rows/wave, zero barriers --------
// Layout A: amp i = (lane<<4)|r ; Layout B: amp i = (r<<6)|lane.
__global__ __launch_bounds__(64) void qae_main(const float* __restrict__ x,
                                               const float2* __restrict__ gt,
                                               float* __restrict__ out, int Btot) {
  __shared__ f2 stc[1024];              // 8KB, wave-private by construction
  const int lane = threadIdx.x;
  const int b0   = blockIdx.x * 2, b1 = b0 + 1;
  const bool has1 = (b1 < Btot);

  // Preload per-lane RZ factors NOW (latency hides under round-1 compute).
  const float2 L1 = gt[102 + lane];
  const float2 L2 = gt[166 + lane];

  // XOR-linear LDS address bases (byte offsets), computed once per wave.
  const int bA8   = swzf(lane << 4) << 3;          // A-pattern writes
  const int sL8   = swzf(lane) << 3;               // B-side: write/read
  const int bCA8  = swzf(cnotL(lane << 4)) << 3;   // T2 gather-read (into A)
  const int bCB8  = swzf(cnotL(lane)) << 3;        // T4 gather-read (into B)

  // Load 2 rows, layout A: g[r] = (row0[i], row1[i]), i = (lane<<4)|r; i>=768 zero.
  f2 g[16];
  f2 ss = (f2){0.f, 0.f};
  const float* x0 = x + (size_t)b0 * DIN;
  const float* x1 = x + (size_t)b1 * DIN;
#pragma unroll
  for (int t = 0; t < 4; ++t) {
    const int idx = lane * 16 + 4 * t;
    float4 va = make_float4(0.f, 0.f, 0.f, 0.f);
    float4 vb = make_float4(0.f, 0.f, 0.f, 0.f);
    if (idx < DIN) {
      va = *reinterpret_cast<const float4*>(x0 + idx);
      if (has1) vb = *reinterpret_cast<const float4*>(x1 + idx);
    }
    g[4*t+0] = (f2){va.x, vb.x}; g[4*t+1] = (f2){va.y, vb.y};
    g[4*t+2] = (f2){va.z, vb.z}; g[4*t+3] = (f2){va.w, vb.w};
#pragma unroll
    for (int k = 0; k < 4; ++k) ss += g[4*t+k] * g[4*t+k];
  }
  ss = wsum2(ss);
  const f2 inv = (f2){1.f / fmaxf(ss.x, 1e-16f), 1.f / fmaxf(ss.y, 1e-16f)};

  float2 cs;
  // ===== layer 1 RY round (w[0..9]) — REAL state, layout A: r bits 3..0 <-> q6..q9 =====
  cs = gt[6]; ry1<3>(g, cs.x, cs.y);
  cs = gt[7]; ry1<2>(g, cs.x, cs.y);
  cs = gt[8]; ry1<1>(g, cs.x, cs.y);
  cs = gt[9]; ry1<0>(g, cs.x, cs.y);
  cs = gt[4]; ry1_shfl<2>(lane, g, cs.x, cs.y);   // q4 <-> lane bit 1
  cs = gt[5]; ry1_shfl<1>(lane, g, cs.x, cs.y);   // q5 <-> lane bit 0

  // T1: A->B (real, rows travel inside the f2 cell)
#pragma unroll
  for (int r = 0; r < 16; ++r) STC8(bA8 ^ (r << 3)) = g[r];
#pragma unroll
  for (int r = 0; r < 16; ++r) g[r] = STC8((swzf(r << 6) << 3) ^ sL8);

  // B: r bits 3..0 <-> q0..q3
  cs = gt[0]; ry1<3>(g, cs.x, cs.y);
  cs = gt[1]; ry1<2>(g, cs.x, cs.y);
  cs = gt[2]; ry1<1>(g, cs.x, cs.y);
  cs = gt[3]; ry1<0>(g, cs.x, cs.y);

  // RZ1 (phi-split): real -> complex. Rf = gt[70+r] (wave-uniform), Lf = L1 (per lane).
  f2 re[16], im[16];
#pragma unroll
  for (int r = 0; r < 16; ++r) {
    const float2 R = gt[70 + r];
    const float kre = R.x * L1.x - R.y * L1.y;
    const float kim = R.x * L1.y + R.y * L1.x;
    re[r] = g[r] * kre;
    im[r] = g[r] * kim;
  }

  // T2: CNOT ring 1 fused into B->A transpose (two b64 passes through 8KB)
#pragma unroll
  for (int r = 0; r < 16; ++r) STC8((swzf(r << 6) << 3) ^ sL8) = re[r];
#pragma unroll
  for (int r = 0; r < 16; ++r) re[r] = STC8(bCA8 ^ (swzf(cnotL(r)) << 3));
#pragma unroll
  for (int r = 0; r < 16; ++r) STC8((swzf(r << 6) << 3) ^ sL8) = im[r];
#pragma unroll
  for (int r = 0; r < 16; ++r) im[r] = STC8(bCA8 ^ (swzf(cnotL(r)) << 3));

  // ===== combined RY round (folded, gt[60..69]), layout A =====
  cs = gt[66]; ry2<3>(re, im, cs.x, cs.y);
  cs = gt[67]; ry2<2>(re, im, cs.x, cs.y);
  cs = gt[68]; ry2<1>(re, im, cs.x, cs.y);
  cs = gt[69]; ry2<0>(re, im, cs.x, cs.y);
  cs = gt[64]; ry1_shfl<2>(lane, re, cs.x, cs.y); ry1_shfl<2>(lane, im, cs.x, cs.y);
  cs = gt[65]; ry1_shfl<1>(lane, re, cs.x, cs.y); ry1_shfl<1>(lane, im, cs.x, cs.y);

  // T3: A->B
#pragma unroll
  for (int r = 0; r < 16; ++r) STC8(bA8 ^ (r << 3)) = re[r];
#pragma unroll
  for (int r = 0; r < 16; ++r) re[r] = STC8((swzf(r << 6) << 3) ^ sL8);
#pragma unroll
  for (int r = 0; r < 16; ++r) STC8(bA8 ^ (r << 3)) = im[r];
#pragma unroll
  for (int r = 0; r < 16; ++r) im[r] = STC8((swzf(r << 6) << 3) ^ sL8);

  cs = gt[60]; ry2<3>(re, im, cs.x, cs.y);
  cs = gt[61]; ry2<2>(re, im, cs.x, cs.y);
  cs = gt[62]; ry2<1>(re, im, cs.x, cs.y);
  cs = gt[63]; ry2<0>(re, im, cs.x, cs.y);

  // RZ2 (phi-split), layout B
#pragma unroll
  for (int r = 0; r < 16; ++r) {
    const float2 R = gt[86 + r];
    const float kre = R.x * L2.x - R.y * L2.y;
    const float kim = R.x * L2.y + R.y * L2.x;
    const f2 nre = re[r] * kre - im[r] * kim;
    im[r] = re[r] * kim + im[r] * kre;
    re[r] = nre;
  }

  // T4: CNOT ring 2, gather read directly into layout B (final RY folded at output)
#pragma unroll
  for (int r = 0; r < 16; ++r) STC8((swzf(r << 6) << 3) ^ sL8) = re[r];
#pragma unroll
  for (int r = 0; r < 16; ++r) re[r] = STC8(bCB8 ^ (swzf(cnotL(r << 6)) << 3));
#pragma unroll
  for (int r = 0; r < 16; ++r) STC8((swzf(r << 6) << 3) ^ sL8) = im[r];
#pragma unroll
  for (int r = 0; r < 16; ++r) im[r] = STC8(bCB8 ^ (swzf(cnotL(r << 6)) << 3));

  // ===== expectation values (layout B), rows packed in f2 =====
  // acc order: [0..5]=X, [6..11]=Y, [12..17]=Z
  f2 a18[18];
#pragma unroll
  for (int k = 0; k < 12; ++k) a18[k] = (f2){0.f, 0.f};

  {
    f2 psum = (f2){0.f, 0.f};
    f2 z0 = (f2){0.f,0.f}, z1 = (f2){0.f,0.f}, z2 = (f2){0.f,0.f}, z3 = (f2){0.f,0.f};
#pragma unroll
    for (int r = 0; r < 16; ++r) {
      const f2 p = re[r] * re[r] + im[r] * im[r];
      psum += p;
      z0 += (r & 8) ? -p : p;
      z1 += (r & 4) ? -p : p;
      z2 += (r & 2) ? -p : p;
      z3 += (r & 1) ? -p : p;
    }
    a18[12] = z0; a18[13] = z1; a18[14] = z2; a18[15] = z3;
    a18[16] = ((lane >> 5) & 1) ? -psum : psum;   // Z q4
    a18[17] = ((lane >> 4) & 1) ? -psum : psum;   // Z q5
  }

  xyr<3>(re, im, a18[0], a18[6]);
  xyr<2>(re, im, a18[1], a18[7]);
  xyr<1>(re, im, a18[2], a18[8]);
  xyr<0>(re, im, a18[3], a18[9]);
  xys<32>(lane, re, im, a18[4], a18[10]);
  xys<16>(lane, re, im, a18[5], a18[11]);

  // --- distributed reduction: 2-step quad pre-reduce, then LDS combine ---
#pragma unroll
  for (int k = 0; k < 18; ++k) {
    f2 v = a18[k];
    v += dppf2<0xB1>(v);     // xor 1
    v += dppf2<0x4E>(v);     // xor 2  -> every lane in a quad holds the quad sum
    a18[k] = v;
  }
  float* red = reinterpret_cast<float*>(stc);     // reuse wave-private LDS (T4 done)
  if ((lane & 3) == 0) {
    const int q = lane >> 2;                      // quad id 0..15
    f2* redf2 = reinterpret_cast<f2*>(red);
#pragma unroll
    for (int k = 0; k < 18; ++k) redf2[q * 20 + k] = a18[k];
  }
  // Lanes 0..35: (c = row, j = observable). Sum 16 quad partials for own acc and
  // the Heisenberg partner (X<->Z), transform, store straight to out.
  if (lane < 36) {
    const int c  = (lane >= 18) ? 1 : 0;
    const int j  = lane - 18 * c;
    const int jq = (j < 6) ? j : ((j < 12) ? j - 6 : j - 12);
    const int jp = (j < 6) ? (j + 12) : ((j >= 12) ? (j - 12) : j);
    float S = 0.f, P = 0.f;
#pragma unroll
    for (int q = 0; q < 16; ++q) {
      S += red[(q * 20 + j ) * 2 + c];
      P += red[(q * 20 + jp) * 2 + c];
    }
    const float fac  = (jq < 4) ? 2.f : 1.f;      // xyr pairs once; xys twice
    const float2 fa  = gt[50 + jq];
    const float invc = c ? inv.y : inv.x;
    float o;
    if (j < 6)       o = (fac * S * fa.x + P * fa.y) * invc;        // X' = c*X + s*Z
    else if (j < 12) o = fac * S * invc;                            // Y' = Y
    else             o = (S * fa.x - fac * P * fa.y) * invc;        // Z' = c*Z - s*X
    if (c == 0 || has1) out[(size_t)(b0 + c) * 18 + j] = o;
  }
}

extern "C" void kernel_launch(void* const* d_in, const int* in_sizes, int n_in,
                              void* d_out, int out_size, void* d_ws, size_t ws_size,
                              hipStream_t stream) {
  const float* x = (const float*)d_in[0];
  const float* w = (const float*)d_in[1];
  float* out = (float*)d_out;
  float2* ws = (float2*)d_ws;
  const int B = in_sizes[0] / DIN;
  qae_prep<<<dim3(1), dim3(1024), 0, stream>>>(w, ws);
  const int grid = (B + 1) / 2;     // 1 wave/block, 2 rows/wave
  qae_main<<<dim3(grid), dim3(64), 0, stream>>>(x, (const float2*)ws, out, B);
}

// Round 17
// 100.480 us; speedup vs baseline: 1.0266x; 1.0266x over previous
//
#include <hip/hip_runtime.h>

#define DIN 768

typedef float f2 __attribute__((ext_vector_type(2)));
typedef int i2v __attribute__((ext_vector_type(2)));

#if __has_builtin(__builtin_amdgcn_permlane32_swap)
#define HAVE_PL32 1
#endif
#if __has_builtin(__builtin_amdgcn_permlane16_swap)
#define HAVE_PL16 1
#endif

__device__ __forceinline__ int f2i(float v) { return __builtin_bit_cast(int, v); }
__device__ __forceinline__ float i2f(int v) { return __builtin_bit_cast(float, v); }

// DPP ctrl: quad_perm xor1 = 0xB1 ; xor2 = 0x4E ; row_ror:4 = 0x124 ; row_ror:8 = 0x128
template<int CTRL>
__device__ __forceinline__ float dppf(float v) {
  const int i = f2i(v);
  return i2f(__builtin_amdgcn_update_dpp(i, i, CTRL, 0xF, 0xF, true));
}
template<int CTRL>
__device__ __forceinline__ f2 dppf2(f2 v) {
  f2 r; r.x = dppf<CTRL>(v.x); r.y = dppf<CTRL>(v.y); return r;
}

// Full 64-lane sum of both f2 components. Zero DS ops. (Used once, for sumsq.)
__device__ __forceinline__ f2 wsum2(f2 v) {
  v += dppf2<0xB1>(v);
  v += dppf2<0x4E>(v);
  v += dppf2<0x124>(v);
  v += dppf2<0x128>(v);
#ifdef HAVE_PL16
  { i2v rx = __builtin_amdgcn_permlane16_swap(f2i(v.x), f2i(v.x), false, false);
    i2v ry = __builtin_amdgcn_permlane16_swap(f2i(v.y), f2i(v.y), false, false);
    v.x = i2f(rx.x) + i2f(rx.y);
    v.y = i2f(ry.x) + i2f(ry.y); }
#else
  v.x += __shfl_xor(v.x, 16); v.y += __shfl_xor(v.y, 16);
#endif
#ifdef HAVE_PL32
  { i2v rx = __builtin_amdgcn_permlane32_swap(f2i(v.x), f2i(v.x), false, false);
    i2v ry = __builtin_amdgcn_permlane32_swap(f2i(v.y), f2i(v.y), false, false);
    v.x = i2f(rx.x) + i2f(rx.y);
    v.y = i2f(ry.x) + i2f(ry.y); }
#else
  v.x += __shfl_xor(v.x, 32); v.y += __shfl_xor(v.y, 32);
#endif
  return v;
}

// xor-shuffle of an f2, VALU-only for masks 1,2,16,32.
template<int MASK>
__device__ __forceinline__ f2 shflx_f2(f2 v, int lane) {
  f2 r;
  if constexpr (MASK == 1) {
    r = dppf2<0xB1>(v);
  } else if constexpr (MASK == 2) {
    r = dppf2<0x4E>(v);
  } else if constexpr (MASK == 16) {
#ifdef HAVE_PL16
    const i2v a = __builtin_amdgcn_permlane16_swap(f2i(v.x), f2i(v.x), false, false);
    const i2v b = __builtin_amdgcn_permlane16_swap(f2i(v.y), f2i(v.y), false, false);
    const bool hi = (lane >> 4) & 1;
    r.x = hi ? i2f(a.x) : i2f(a.y);
    r.y = hi ? i2f(b.x) : i2f(b.y);
#else
    r.x = __shfl_xor(v.x, 16); r.y = __shfl_xor(v.y, 16);
#endif
  } else if constexpr (MASK == 32) {
#ifdef HAVE_PL32
    const i2v a = __builtin_amdgcn_permlane32_swap(f2i(v.x), f2i(v.x), false, false);
    const i2v b = __builtin_amdgcn_permlane32_swap(f2i(v.y), f2i(v.y), false, false);
    const bool lo = lane < 32;
    r.x = lo ? i2f(a.y) : i2f(a.x);
    r.y = lo ? i2f(b.y) : i2f(b.x);
#else
    r.x = __shfl_xor(v.x, 32); r.y = __shfl_xor(v.y, 32);
#endif
  } else {
    r.x = __shfl_xor(v.x, MASK); r.y = __shfl_xor(v.y, MASK);
  }
  return r;
}

// LDS address swizzle (GF(2)-linear: swzf(a^b) = swzf(a)^swzf(b))
__device__ __forceinline__ int swzf(int i) { return i ^ ((i >> 4) & 31); }

// Composite gather map of the CNOT ring CNOT(0,1)..CNOT(9,0): Final[i] = In[cnotL(i)]
// GF(2)-linear: every output bit is an XOR of input bits.
__device__ __forceinline__ int cnotL(int i) {
  const int b9 = (i >> 9) & 1;
  const int b8 = (i >> 8) & 1;
  const int b0 = i & 1;
  return ((i ^ (i >> 1)) & 0xFF) | ((b8 ^ b9 ^ b0) << 8) | ((b9 ^ b0) << 9);
}

// RY on a 16-reg component array (rows packed in f2). Real 2x2 acts per component.
template<int RB>
__device__ __forceinline__ void ry1(f2 (&a)[16], float c, float s) {
#pragma unroll
  for (int r = 0; r < 16; ++r) {
    if (!(r & (1 << RB))) {
      const int p = r | (1 << RB);
      const f2 a0 = a[r], a1 = a[p];
      a[r] = a0 * c - a1 * s;
      a[p] = a1 * c + a0 * s;
    }
  }
}
template<int RB>
__device__ __forceinline__ void ry2(f2 (&re)[16], f2 (&im)[16], float c, float s) {
  ry1<RB>(re, c, s);
  ry1<RB>(im, c, s);
}
template<int MASK>
__device__ __forceinline__ void ry1_shfl(int lane, f2 (&a)[16], float c, float s) {
  const float ss = (lane & MASK) ? s : -s;
#pragma unroll
  for (int r = 0; r < 16; ++r) {
    const f2 p = shflx_f2<MASK>(a[r], lane);
    a[r] = a[r] * c + p * ss;
  }
}

// X/Y accumulate, register-pair qubit (each unordered pair once -> fac 2 at output)
template<int RB>
__device__ __forceinline__ void xyr(const f2 (&re)[16], const f2 (&im)[16], f2& aX, f2& aY) {
#pragma unroll
  for (int r = 0; r < 16; ++r) {
    if (!(r & (1 << RB))) {
      const int p = r | (1 << RB);
      aX += re[r] * re[p] + im[r] * im[p];
      aY += re[r] * im[p] - im[r] * re[p];
    }
  }
}
// X/Y accumulate, lane-bit qubit (each ordered pair counted -> net 2x already)
template<int MASK>
__device__ __forceinline__ void xys(int lane, const f2 (&re)[16], const f2 (&im)[16], f2& aX, f2& aY) {
  const float sgn = (lane & MASK) ? -1.f : 1.f;
#pragma unroll
  for (int r = 0; r < 16; ++r) {
    const f2 pr = shflx_f2<MASK>(re[r], lane);
    const f2 pi = shflx_f2<MASK>(im[r], lane);
    aX += re[r] * pr + im[r] * pi;
    aY += (re[r] * pi - im[r] * pr) * sgn;
  }
}

// ---------------- prep kernel: all weight-dependent transcendentals ----------------
// ws layout (float2): [0..69] gate table; [70..1093] rz1 per-amp (cos,sin);
//                     [1094..2117] rz2 per-amp (cos,sin)
__global__ void qae_prep(const float* __restrict__ w, float2* __restrict__ ws) {
  const int i = threadIdx.x;          // 0..1023
  if (i < 50) {                       // half-angle gate coefficients
    float s, c; __sincosf(0.5f * w[i], &s, &c);
    ws[i] = make_float2(c, s);
  } else if (i < 56) {                // FULL angle: Heisenberg output transform w[50..55]
    float s, c; __sincosf(w[i], &s, &c);
    ws[i] = make_float2(c, s);
  } else if (i < 60) {
    ws[i] = make_float2(1.f, 0.f);    // unused
  } else if (i < 70) {                // folded RY_b(layer1)+RY_c(layer2)
    const int q = i - 60;
    float s, c; __sincosf(0.5f * (w[20 + q] + w[30 + q]), &s, &c);
    ws[i] = make_float2(c, s);
  }
  // per-amplitude RZ phases: phi(i) = sum_b (bit b of i ? +.5 : -.5) * w[off + 9 - b]
  float p1 = 0.f, p2 = 0.f;
#pragma unroll
  for (int b = 0; b < 10; ++b) {
    const float sg = ((i >> b) & 1) ? 0.5f : -0.5f;
    p1 += sg * w[10 + 9 - b];
    p2 += sg * w[40 + 9 - b];
  }
  float s, c;
  __sincosf(p1, &s, &c); ws[70 + i]        = make_float2(c, s);
  __sincosf(p2, &s, &c); ws[70 + 1024 + i] = make_float2(c, s);
}

// LDS access at a byte offset (bases XOR compile-time constants)
#define STC8(boff) (*reinterpret_cast<f2*>(reinterpret_cast<char*>(stc) + (boff)))

// -------- main kernel: ONE wave per block (8KB LDS), 2 rows/wave, zero barriers --------
__global__ __launch_bounds__(64) void qae_main(const float* __restrict__ x,
                                               const float2* __restrict__ gt,
                                               float* __restrict__ out, int Btot) {
  __shared__ f2 stc[1024];              // 8KB, wave-private by construction
  const int lane = threadIdx.x;
  const int b0   = blockIdx.x * 2, b1 = b0 + 1;
  const bool has1 = (b1 < Btot);
  const float2* rz1 = gt + 70;
  const float2* rz2 = gt + 70 + 1024;

  // ---- XOR-linear LDS address bases (byte offsets), computed once per wave ----
  const int bA8   = swzf(lane << 4) << 3;          // A-pattern writes
  const int sL8   = swzf(lane) << 3;               // B-side: write/read
  const int bCA8  = swzf(cnotL(lane << 4)) << 3;   // T2 gather-read (into A)
  const int bCB8  = swzf(cnotL(lane)) << 3;        // T4 gather-read (into B)

  // Load 2 rows, layout A: g[r] = (row0[i], row1[i]), i = (lane<<4)|r; i>=768 zero.
  f2 g[16];
  f2 ss = (f2){0.f, 0.f};
  const float* x0 = x + (size_t)b0 * DIN;
  const float* x1 = x + (size_t)b1 * DIN;
#pragma unroll
  for (int t = 0; t < 4; ++t) {
    const int idx = lane * 16 + 4 * t;
    float4 va = make_float4(0.f, 0.f, 0.f, 0.f);
    float4 vb = make_float4(0.f, 0.f, 0.f, 0.f);
    if (idx < DIN) {
      va = *reinterpret_cast<const float4*>(x0 + idx);
      if (has1) vb = *reinterpret_cast<const float4*>(x1 + idx);
    }
    g[4*t+0] = (f2){va.x, vb.x}; g[4*t+1] = (f2){va.y, vb.y};
    g[4*t+2] = (f2){va.z, vb.z}; g[4*t+3] = (f2){va.w, vb.w};
#pragma unroll
    for (int k = 0; k < 4; ++k) ss += g[4*t+k] * g[4*t+k];
  }
  ss = wsum2(ss);
  const f2 inv = (f2){1.f / fmaxf(ss.x, 1e-16f), 1.f / fmaxf(ss.y, 1e-16f)};

  float2 cs;
  // ===== layer 1 RY round (w[0..9]) — REAL state, layout A: r bits 3..0 <-> q6..q9 =====
  cs = gt[6]; ry1<3>(g, cs.x, cs.y);
  cs = gt[7]; ry1<2>(g, cs.x, cs.y);
  cs = gt[8]; ry1<1>(g, cs.x, cs.y);
  cs = gt[9]; ry1<0>(g, cs.x, cs.y);
  cs = gt[4]; ry1_shfl<2>(lane, g, cs.x, cs.y);   // q4 <-> lane bit 1
  cs = gt[5]; ry1_shfl<1>(lane, g, cs.x, cs.y);   // q5 <-> lane bit 0

  // T1: A->B (real, rows travel inside the f2 cell)
#pragma unroll
  for (int r = 0; r < 16; ++r) STC8(bA8 ^ (r << 3)) = g[r];
#pragma unroll
  for (int r = 0; r < 16; ++r) g[r] = STC8((swzf(r << 6) << 3) ^ sL8);

  // B: r bits 3..0 <-> q0..q3
  cs = gt[0]; ry1<3>(g, cs.x, cs.y);
  cs = gt[1]; ry1<2>(g, cs.x, cs.y);
  cs = gt[2]; ry1<1>(g, cs.x, cs.y);
  cs = gt[3]; ry1<0>(g, cs.x, cs.y);

  // RZ1 (table): real -> complex, rows packed: re/im separate register files
  f2 re[16], im[16];
#pragma unroll
  for (int r = 0; r < 16; ++r) {
    const float2 t = rz1[(r << 6) | lane];
    re[r] = g[r] * t.x;
    im[r] = g[r] * t.y;
  }

  // T2: CNOT ring 1 fused into B->A transpose (two b64 passes through 8KB)
#pragma unroll
  for (int r = 0; r < 16; ++r) STC8((swzf(r << 6) << 3) ^ sL8) = re[r];
#pragma unroll
  for (int r = 0; r < 16; ++r) re[r] = STC8(bCA8 ^ (swzf(cnotL(r)) << 3));
#pragma unroll
  for (int r = 0; r < 16; ++r) STC8((swzf(r << 6) << 3) ^ sL8) = im[r];
#pragma unroll
  for (int r = 0; r < 16; ++r) im[r] = STC8(bCA8 ^ (swzf(cnotL(r)) << 3));

  // ===== combined RY round (folded, gt[60..69]), layout A =====
  cs = gt[66]; ry2<3>(re, im, cs.x, cs.y);
  cs = gt[67]; ry2<2>(re, im, cs.x, cs.y);
  cs = gt[68]; ry2<1>(re, im, cs.x, cs.y);
  cs = gt[69]; ry2<0>(re, im, cs.x, cs.y);
  cs = gt[64]; ry1_shfl<2>(lane, re, cs.x, cs.y); ry1_shfl<2>(lane, im, cs.x, cs.y);
  cs = gt[65]; ry1_shfl<1>(lane, re, cs.x, cs.y); ry1_shfl<1>(lane, im, cs.x, cs.y);

  // T3: A->B
#pragma unroll
  for (int r = 0; r < 16; ++r) STC8(bA8 ^ (r << 3)) = re[r];
#pragma unroll
  for (int r = 0; r < 16; ++r) re[r] = STC8((swzf(r << 6) << 3) ^ sL8);
#pragma unroll
  for (int r = 0; r < 16; ++r) STC8(bA8 ^ (r << 3)) = im[r];
#pragma unroll
  for (int r = 0; r < 16; ++r) im[r] = STC8((swzf(r << 6) << 3) ^ sL8);

  cs = gt[60]; ry2<3>(re, im, cs.x, cs.y);
  cs = gt[61]; ry2<2>(re, im, cs.x, cs.y);
  cs = gt[62]; ry2<1>(re, im, cs.x, cs.y);
  cs = gt[63]; ry2<0>(re, im, cs.x, cs.y);

  // RZ2 (table)
#pragma unroll
  for (int r = 0; r < 16; ++r) {
    const float2 t = rz2[(r << 6) | lane];
    const f2 nre = re[r] * t.x - im[r] * t.y;
    im[r] = re[r] * t.y + im[r] * t.x;
    re[r] = nre;
  }

  // T4: CNOT ring 2, gather read directly into layout B (final RY folded at output)
#pragma unroll
  for (int r = 0; r < 16; ++r) STC8((swzf(r << 6) << 3) ^ sL8) = re[r];
#pragma unroll
  for (int r = 0; r < 16; ++r) re[r] = STC8(bCB8 ^ (swzf(cnotL(r << 6)) << 3));
#pragma unroll
  for (int r = 0; r < 16; ++r) STC8((swzf(r << 6) << 3) ^ sL8) = im[r];
#pragma unroll
  for (int r = 0; r < 16; ++r) im[r] = STC8(bCB8 ^ (swzf(cnotL(r << 6)) << 3));

  // ===== expectation values (layout B), rows packed in f2 =====
  // acc order: [0..5]=X, [6..11]=Y, [12..17]=Z
  f2 a18[18];
#pragma unroll
  for (int k = 0; k < 12; ++k) a18[k] = (f2){0.f, 0.f};

  {
    f2 psum = (f2){0.f, 0.f};
    f2 z0 = (f2){0.f,0.f}, z1 = (f2){0.f,0.f}, z2 = (f2){0.f,0.f}, z3 = (f2){0.f,0.f};
#pragma unroll
    for (int r = 0; r < 16; ++r) {
      const f2 p = re[r] * re[r] + im[r] * im[r];
      psum += p;
      z0 += (r & 8) ? -p : p;
      z1 += (r & 4) ? -p : p;
      z2 += (r & 2) ? -p : p;
      z3 += (r & 1) ? -p : p;
    }
    a18[12] = z0; a18[13] = z1; a18[14] = z2; a18[15] = z3;
    a18[16] = ((lane >> 5) & 1) ? -psum : psum;   // Z q4
    a18[17] = ((lane >> 4) & 1) ? -psum : psum;   // Z q5
  }

  xyr<3>(re, im, a18[0], a18[6]);
  xyr<2>(re, im, a18[1], a18[7]);
  xyr<1>(re, im, a18[2], a18[8]);
  xyr<0>(re, im, a18[3], a18[9]);
  xys<32>(lane, re, im, a18[4], a18[10]);
  xys<16>(lane, re, im, a18[5], a18[11]);

  // --- distributed reduction: 2-step quad pre-reduce, then LDS combine ---
#pragma unroll
  for (int k = 0; k < 18; ++k) {
    f2 v = a18[k];
    v += dppf2<0xB1>(v);     // xor 1
    v += dppf2<0x4E>(v);     // xor 2  -> every lane in a quad holds the quad sum
    a18[k] = v;
  }
  float* red = reinterpret_cast<float*>(stc);     // reuse wave-private LDS (T4 done)
  if ((lane & 3) == 0) {
    const int q = lane >> 2;                      // quad id 0..15
    f2* redf2 = reinterpret_cast<f2*>(red);
#pragma unroll
    for (int k = 0; k < 18; ++k) redf2[q * 20 + k] = a18[k];
  }
  // Lanes 0..35: (c = row, j = observable). Sum 16 quad partials for own acc and
  // the Heisenberg partner (X<->Z), transform, store straight to out.
  if (lane < 36) {
    const int c  = (lane >= 18) ? 1 : 0;
    const int j  = lane - 18 * c;
    const int jq = (j < 6) ? j : ((j < 12) ? j - 6 : j - 12);
    const int jp = (j < 6) ? (j + 12) : ((j >= 12) ? (j - 12) : j);
    float S = 0.f, P = 0.f;
#pragma unroll
    for (int q = 0; q < 16; ++q) {
      S += red[(q * 20 + j ) * 2 + c];
      P += red[(q * 20 + jp) * 2 + c];
    }
    const float fac  = (jq < 4) ? 2.f : 1.f;      // xyr pairs once; xys twice
    const float2 fa  = gt[50 + jq];
    const float invc = c ? inv.y : inv.x;
    float o;
    if (j < 6)       o = (fac * S * fa.x + P * fa.y) * invc;        // X' = c*X + s*Z
    else if (j < 12) o = fac * S * invc;                            // Y' = Y
    else             o = (S * fa.x - fac * P * fa.y) * invc;        // Z' = c*Z - s*X
    if (c == 0 || has1) out[(size_t)(b0 + c) * 18 + j] = o;
  }
}

extern "C" void kernel_launch(void* const* d_in, const int* in_sizes, int n_in,
                              void* d_out, int out_size, void* d_ws, size_t ws_size,
                              hipStream_t stream) {
  const float* x = (const float*)d_in[0];
  const float* w = (const float*)d_in[1];
  float* out = (float*)d_out;
  float2* ws = (float2*)d_ws;
  const int B = in_sizes[0] / DIN;
  qae_prep<<<dim3(1), dim3(1024), 0, stream>>>(w, ws);
  const int grid = (B + 1) / 2;     // 1 wave/block, 2 rows/wave
  qae_main<<<dim3(grid), dim3(64), 0, stream>>>(x, (const float2*)ws, out, B);
}